// Round 17
// baseline (180.760 us; speedup 1.0000x reference)
//
#include <hip/hip_runtime.h>
#include <hip/hip_bf16.h>
#include <math.h>

typedef __hip_bfloat16 bf16;
typedef short v8s __attribute__((ext_vector_type(8)));
typedef float v4f __attribute__((ext_vector_type(4)));

#define B_TOK 4096
#define E_EXP 8
#define D_IN  768
#define D_H   2048
#define D_OUT 768
#define MAXT  72      // max M-tiles of 128 over all experts (64 + 7 skew, padded)

// ---------------------------------------------------------------- helpers
__device__ __forceinline__ void gl_lds16(const bf16* g, bf16* l) {
  __builtin_amdgcn_global_load_lds(
      (const __attribute__((address_space(1))) unsigned int*)g,
      (__attribute__((address_space(3))) unsigned int*)l, 16, 0, 0);
}

// 64x64 LDS tile transpose (R10-verified swizzle; 256B-segment reads,
// 64B-cluster writes).  tile rows = 72 bf16 (144B).
__device__ __forceinline__ void transpose_tile64(
    const float* __restrict__ W, bf16* __restrict__ Wt,
    int K, int N, int e, int k0, int n0, int t, bf16 (*tile)[72]) {
  const int w = t >> 6, l = t & 63;
  const float* Wp = W + (size_t)e * K * N;
  #pragma unroll
  for (int p = 0; p < 4; ++p) {
    int k_loc = w * 16 + p * 4 + (l >> 4);
    int nn = (l & 15) * 4;
    float4 v = *(const float4*)(Wp + (size_t)(k0 + k_loc) * N + n0 + nn);
    float vv[4] = {v.x, v.y, v.z, v.w};
    #pragma unroll
    for (int i = 0; i < 4; ++i) {
      int n_loc = nn + i;
      int phys = (k_loc >> 3) ^ ((n_loc >> 2) & 7);
      tile[n_loc][phys * 8 + (k_loc & 7)] = __float2bfloat16(vv[i]);
    }
  }
  __syncthreads();
  bf16* Wtp = Wt + (size_t)e * N * K;
  const int nsub = l >> 2;
  #pragma unroll
  for (int p2 = 0; p2 < 2; ++p2) {
    int c = (l & 3) + p2 * 4;
    int n_loc = w * 16 + nsub;
    int phys = c ^ ((n_loc >> 2) & 7);
    v8s val = *(const v8s*)&tile[n_loc][phys * 8];
    *(v8s*)(Wtp + (size_t)(n0 + n_loc) * K + k0 + c * 8) = val;
  }
}

// ---------------------------------------------------------------- prep1:
// blocks [0,3072): W1 transpose; [3072,4096): gate + x->bf16.
__global__ __launch_bounds__(256)
void prep_kernel(const float* __restrict__ x, const float* __restrict__ wg,
                 const float* __restrict__ W1, bf16* __restrict__ W1t,
                 bf16* __restrict__ xb, float* __restrict__ gates,
                 int* __restrict__ tidx) {
  __shared__ bf16 tile[64][72];
  const int b = blockIdx.x;
  const int t = threadIdx.x;
  if (b < 3072) {
    int e = b / 384, rem = b % 384;
    int kb = rem % 12, nb = rem / 12;        // K=768: 12 k-tiles; N=2048: 32 n-tiles
    transpose_tile64(W1, W1t, D_IN, D_H, e, kb * 64, nb * 64, t, tile);
  } else {
    int gt = (b - 3072) * 256 + t;
    int tok = gt >> 6, l = gt & 63;
    const float* xr = x + (size_t)tok * D_IN;
    bf16* xbr = xb + (size_t)tok * D_IN;
    float acc[8] = {0.f,0.f,0.f,0.f,0.f,0.f,0.f,0.f};
    #pragma unroll
    for (int i = 0; i < 3; ++i) {
      int k0 = i * 256 + l * 4;
      float4 v = *(const float4*)(xr + k0);
      union { bf16 h[4]; uint2 u; } pk;
      pk.h[0] = __float2bfloat16(v.x); pk.h[1] = __float2bfloat16(v.y);
      pk.h[2] = __float2bfloat16(v.z); pk.h[3] = __float2bfloat16(v.w);
      *(uint2*)(xbr + k0) = pk.u;
      float xv[4] = {v.x, v.y, v.z, v.w};
      #pragma unroll
      for (int j = 0; j < 4; ++j) {
        const float* wr = wg + (size_t)(k0 + j) * 8;
        float4 w0 = *(const float4*)wr;
        float4 w1 = *(const float4*)(wr + 4);
        acc[0] += xv[j] * w0.x; acc[1] += xv[j] * w0.y;
        acc[2] += xv[j] * w0.z; acc[3] += xv[j] * w0.w;
        acc[4] += xv[j] * w1.x; acc[5] += xv[j] * w1.y;
        acc[6] += xv[j] * w1.z; acc[7] += xv[j] * w1.w;
      }
    }
    #pragma unroll
    for (int d = 1; d < 64; d <<= 1)
      #pragma unroll
      for (int e2 = 0; e2 < 8; ++e2) acc[e2] += __shfl_xor(acc[e2], d);
    if (l == 0) {
      int i1 = 0; float v1 = acc[0];
      #pragma unroll
      for (int e2 = 1; e2 < 8; ++e2) if (acc[e2] > v1) { v1 = acc[e2]; i1 = e2; }
      int i2 = -1; float v2 = -1e30f;
      #pragma unroll
      for (int e2 = 0; e2 < 8; ++e2) if (e2 != i1 && acc[e2] > v2) { v2 = acc[e2]; i2 = e2; }
      float ex = __expf(v2 - v1);
      float g1 = 1.f / (1.f + ex), g2 = ex / (1.f + ex);
      gates[2 * tok] = g1; gates[2 * tok + 1] = g2;
      tidx[2 * tok] = i1;  tidx[2 * tok + 1] = i2;
    }
  }
}

// ---------------------------------------------- single-block: histogram + scan +
// slot assignment + counts/offsets + tile map + aux loss.  256 threads.
__global__ void finalize_kernel(const int* __restrict__ tidx, const float* __restrict__ gates,
                                int* __restrict__ cnt_off, int* __restrict__ row_ids,
                                int* __restrict__ pos, int* __restrict__ tmap,
                                float* __restrict__ loss_out) {
  __shared__ int   hcnt[256][9];
  __shared__ float himp[256][9];
  __shared__ int   tot[8], off[8];
  __shared__ float itot[8];
  int t = threadIdx.x;
  #pragma unroll
  for (int e = 0; e < 8; ++e) { hcnt[t][e] = 0; himp[t][e] = 0.f; }
  __syncthreads();
  for (int i = 0; i < 32; ++i) {
    int idx = t * 32 + i;
    int e = tidx[idx];
    hcnt[t][e] += 1;
    himp[t][e] += gates[idx];
  }
  __syncthreads();
  if (t < 8) {
    int run = 0; float s = 0.f;
    for (int j = 0; j < 256; ++j) {
      int c = hcnt[j][t];
      hcnt[j][t] = run;
      run += c;
      s += himp[j][t];
    }
    tot[t] = run; itot[t] = s;
  }
  __syncthreads();
  if (t == 0) {
    int o = 0;
    float mi = 0.f, ml = 0.f;
    for (int e = 0; e < 8; ++e) {
      off[e] = o; o += tot[e];
      cnt_off[e] = tot[e]; cnt_off[8 + e] = off[e];
      mi += itot[e]; ml += (float)tot[e];
    }
    mi *= 0.125f; ml *= 0.125f;
    float vi = 0.f, vl = 0.f;
    for (int e = 0; e < 8; ++e) {
      float d = itot[e] - mi;        vi += d * d;
      float d2 = (float)tot[e] - ml; vl += d2 * d2;
    }
    vi /= 7.f; vl /= 7.f;
    *loss_out = 0.01f * (vi / (mi * mi + 1e-10f) + vl / (ml * ml + 1e-10f));
    int nt = 0;
    for (int e = 0; e < 8; ++e)
      for (int tt = 0; tt < (tot[e] + 127) >> 7; ++tt) {
        tmap[nt] = e; tmap[MAXT + nt] = tt; ++nt;
      }
    for (; nt < MAXT; ++nt) tmap[nt] = -1;
  }
  __syncthreads();
  for (int i = 0; i < 32; ++i) {
    int idx = t * 32 + i;
    int e = tidx[idx];
    int slot = off[e] + hcnt[t][e];
    hcnt[t][e] += 1;
    row_ids[slot] = idx >> 1;
    pos[idx] = slot;
  }
}

// ---------------------------------------------------------------- GEMM1 (R15)
// 128x128 tile, BK=32, 256 threads, 2-buffer counted-vmcnt(4), 32 KiB LDS ->
// 4 blocks/CU.  Chunk swizzle p = c ^ ((row>>1)&3) (verified R8-R15).
// DOTRANS: extra grid rows transpose W2 (rides with GEMM1).
template<int KDIM, bool GATHER, bool GELU, bool DOTRANS>
__global__ __launch_bounds__(256, 4)
void gemm_bk32(const bf16* __restrict__ Ab, const bf16* __restrict__ Wt,
               const float* __restrict__ bias, bf16* __restrict__ Outb,
               const int* __restrict__ row_ids, const int* __restrict__ cnt_off,
               const int* __restrict__ tmap, const int N,
               const float* __restrict__ Wsrc, bf16* __restrict__ Wdst) {
  constexpr int BK = 32, BM = 128, BN = 128;
  constexpr int NK = KDIM / BK;
  static_assert(NK % 2 == 0 && NK >= 4, "NK even, >=4");
  __shared__ __align__(16) bf16 lds[2][(BM + BN) * BK];   // 2 x 16 KiB
  const int t = (int)threadIdx.x, w = t >> 6, l = t & 63;
  if (DOTRANS && blockIdx.y >= MAXT) {
    int tid = (blockIdx.y - MAXT) * gridDim.x + blockIdx.x;   // 0..767
    int e = tid / 96, r = tid % 96;
    int kb = r % 8, nb = r / 8;                                // 8 x 256k, 12 x 64n
    bf16 (*tile)[72] = (bf16(*)[72])&lds[0][0];
    #pragma unroll 1
    for (int sub = 0; sub < 4; ++sub) {
      transpose_tile64(Wsrc, Wdst, D_H, D_OUT, e, kb * 256 + sub * 64, nb * 64, t, tile);
      __syncthreads();
    }
    return;
  }
  const int ti = blockIdx.y;
  const int e = tmap[ti];
  if (e < 0) return;
  const int rowb = tmap[MAXT + ti];
  const int cnt = cnt_off[e];
  const int off = cnt_off[8 + e];
  const int colb = blockIdx.x;
  const int cs = (l & 3) ^ ((l >> 3) & 3);   // pre-swizzled source chunk (of 4)
  const bf16* gA[2];
  const bf16* gB[2];
  #pragma unroll
  for (int it = 0; it < 2; ++it) {
    int rt = (it * 4 + w) * 16 + (l >> 2);   // slab*16 + row-in-slab
    int r = rowb * BM + rt;
    int rc = r < cnt ? r : cnt - 1;
    long arow = GATHER ? (long)row_ids[off + rc] : (long)(off + rc);
    gA[it] = Ab + arow * (long)KDIM + cs * 8;
    gB[it] = Wt + ((size_t)e * N + (size_t)colb * BN + rt) * KDIM + cs * 8;
  }
  v4f acc[4][4] = {};
  const int wm = w >> 1, wn = w & 1;

#define STAGE(b, k0) do {                                                   \
    _Pragma("unroll")                                                       \
    for (int it = 0; it < 2; ++it)                                          \
      gl_lds16(gA[it] + (k0), &lds[b][(it * 4 + w) * 512]);                 \
    _Pragma("unroll")                                                       \
    for (int it = 0; it < 2; ++it)                                          \
      gl_lds16(gB[it] + (k0), &lds[b][BM * BK + (it * 4 + w) * 512]);       \
  } while (0)

#define COMPUTE(b) do {                                                     \
    __builtin_amdgcn_s_setprio(1);                                          \
    v8s af[4], bfr[4];                                                      \
    const int p = (l >> 4) ^ ((l >> 1) & 3);                                \
    _Pragma("unroll")                                                       \
    for (int fm = 0; fm < 4; ++fm) {                                        \
      int row = wm * 64 + fm * 16 + (l & 15);                               \
      af[fm] = *(const v8s*)(&lds[b][0] + row * BK + p * 8);                \
    }                                                                       \
    _Pragma("unroll")                                                       \
    for (int fn = 0; fn < 4; ++fn) {                                        \
      int row = wn * 64 + fn * 16 + (l & 15);                               \
      bfr[fn] = *(const v8s*)(&lds[b][BM * BK] + row * BK + p * 8);         \
    }                                                                       \
    _Pragma("unroll")                                                       \
    for (int fm = 0; fm < 4; ++fm)                                          \
      _Pragma("unroll")                                                     \
      for (int fn = 0; fn < 4; ++fn)                                        \
        acc[fm][fn] = __builtin_amdgcn_mfma_f32_16x16x32_bf16(af[fm], bfr[fn], acc[fm][fn], 0, 0, 0); \
    __builtin_amdgcn_s_setprio(0);                                          \
  } while (0)

#define SB    __builtin_amdgcn_sched_barrier(0)
#define BARR  __builtin_amdgcn_s_barrier()
#define WAIT4 asm volatile("s_waitcnt vmcnt(4)" ::: "memory")
#define WAITZ asm volatile("s_waitcnt vmcnt(0)" ::: "memory")

  STAGE(0, 0);
  #pragma unroll 1
  for (int ks = 0; ks < NK - 2; ks += 2) {
    STAGE(1, (ks + 1) * BK);
    WAIT4; SB; BARR; SB;
    COMPUTE(0);
    BARR; SB;
    STAGE(0, (ks + 2) * BK);
    WAIT4; SB; BARR; SB;
    COMPUTE(1);
    BARR; SB;
  }
  STAGE(1, (NK - 1) * BK);
  WAIT4; SB; BARR; SB;
  COMPUTE(0);
  WAITZ; SB; BARR; SB;
  COMPUTE(1);
  BARR; SB;                      // protect epilogue LDS reuse
#undef STAGE
#undef COMPUTE
#undef WAIT4
#undef WAITZ

  // ---- epilogue: per-wave LDS transpose -> bias(+gelu) -> coalesced 16B stores
  float* eps = (float*)(&lds[0][0]) + w * (16 * 68);
  const float* bp = bias + (size_t)e * N + (size_t)colb * BN + wn * 64 + (l & 7) * 8;
  float bv[8];
  #pragma unroll
  for (int jj = 0; jj < 8; ++jj) bv[jj] = bp[jj];
  #pragma unroll
  for (int fm = 0; fm < 4; ++fm) {
    #pragma unroll
    for (int fn = 0; fn < 4; ++fn)
      #pragma unroll
      for (int q = 0; q < 4; ++q)
        eps[((l >> 4) * 4 + q) * 68 + fn * 16 + (l & 15)] = acc[fm][fn][q];
    #pragma unroll
    for (int half = 0; half < 2; ++half) {
      int row = (l >> 3) + 8 * half;
      int r = rowb * BM + wm * 64 + fm * 16 + row;
      if (r < cnt) {
        const float* rp = eps + row * 68 + (l & 7) * 8;
        union { bf16 h[8]; uint4 u; } pk;
        #pragma unroll
        for (int jj = 0; jj < 8; ++jj) {
          float v = rp[jj] + bv[jj];
          if (GELU) {
            float u = 0.7978845608028654f * (v + 0.044715f * v * v * v);
            float th = 1.f - 2.f / (__expf(2.f * u) + 1.f);   // tanh(u)
            v = 0.5f * v * (1.f + th);
          }
          pk.h[jj] = __float2bfloat16(v);
        }
        *(uint4*)(Outb + (size_t)(off + r) * N + (size_t)colb * BN + wn * 64 + (l & 7) * 8) = pk.u;
      }
    }
  }
#undef SB
#undef BARR
}

// ---------------------------------------------------------------- GEMM2: direct-B
// 128x128 tile, BK=32.  A staged via gl_lds (2-buffer, verified swizzle);
// B loaded global->VGPR per wave (4 x dwordx4/thread/K-step, L2-resident
// panels), double-buffered in registers.  Unified vmcnt(6) (2 A + 4 B per
// step).  LDS = A only (~17.5 KiB incl. epilogue scratch) -> 3 blocks/CU.
template<int KDIM, bool GELU>
__global__ __launch_bounds__(256, 3)
void gemm_directb(const bf16* __restrict__ Ab, const bf16* __restrict__ Wt,
                  const float* __restrict__ bias, bf16* __restrict__ Outb,
                  const int* __restrict__ cnt_off, const int* __restrict__ tmap,
                  const int N) {
  constexpr int BK = 32, BM = 128;
  constexpr int NK = KDIM / BK;
  static_assert(NK % 2 == 0 && NK >= 4, "NK even, >=4");
  __shared__ __align__(16) bf16 lds[9216];       // A bufs @0,@4608 + epilogue scratch
  const int t = (int)threadIdx.x, w = t >> 6, l = t & 63;
  const int ti = blockIdx.y;
  const int e = tmap[ti];
  if (e < 0) return;
  const int rowb = tmap[MAXT + ti];
  const int cnt = cnt_off[e];
  const int off = cnt_off[8 + e];
  const int colb = blockIdx.x;
  const int cs = (l & 3) ^ ((l >> 3) & 3);
  const int wm = w >> 1, wn = w & 1;
  const bf16* gA[2];
  #pragma unroll
  for (int it = 0; it < 2; ++it) {
    int rt = (it * 4 + w) * 16 + (l >> 2);
    int r = rowb * BM + rt;
    int rc = r < cnt ? r : cnt - 1;
    gA[it] = Ab + (long)(off + rc) * KDIM + cs * 8;
  }
  const bf16* gBp[4];
  #pragma unroll
  for (int fn = 0; fn < 4; ++fn) {
    int n = colb * 128 + wn * 64 + fn * 16 + (l & 15);
    gBp[fn] = Wt + ((size_t)e * N + n) * KDIM + (l >> 4) * 8;
  }
  v4f acc[4][4] = {};
  v8s bA[4], bB[4];

#define STAGEA(boff, k0) do {                                               \
    _Pragma("unroll")                                                       \
    for (int it = 0; it < 2; ++it)                                          \
      gl_lds16(gA[it] + (k0), lds + (boff) + (it * 4 + w) * 512);           \
  } while (0)
#define LOADB(dst, k0) do {                                                 \
    _Pragma("unroll")                                                       \
    for (int fn = 0; fn < 4; ++fn)                                          \
      dst[fn] = *(const v8s*)(gBp[fn] + (k0));                              \
  } while (0)
#define COMPUTE(boff, bset) do {                                            \
    __builtin_amdgcn_s_setprio(1);                                          \
    v8s af[4];                                                              \
    const int p = (l >> 4) ^ ((l >> 1) & 3);                                \
    _Pragma("unroll")                                                       \
    for (int fm = 0; fm < 4; ++fm) {                                        \
      int row = wm * 64 + fm * 16 + (l & 15);                               \
      af[fm] = *(const v8s*)(lds + (boff) + row * BK + p * 8);              \
    }                                                                       \
    _Pragma("unroll")                                                       \
    for (int fm = 0; fm < 4; ++fm)                                          \
      _Pragma("unroll")                                                     \
      for (int fn = 0; fn < 4; ++fn)                                        \
        acc[fm][fn] = __builtin_amdgcn_mfma_f32_16x16x32_bf16(af[fm], bset[fn], acc[fm][fn], 0, 0, 0); \
    __builtin_amdgcn_s_setprio(0);                                          \
  } while (0)

#define SB    __builtin_amdgcn_sched_barrier(0)
#define BARR  __builtin_amdgcn_s_barrier()
#define WAIT6 asm volatile("s_waitcnt vmcnt(6)" ::: "memory")
#define WAITZ asm volatile("s_waitcnt vmcnt(0)" ::: "memory")

  STAGEA(0, 0);
  LOADB(bA, 0);
  #pragma unroll 1
  for (int ks = 0; ks < NK - 2; ks += 2) {
    STAGEA(4608, (ks + 1) * BK);
    LOADB(bB, (ks + 1) * BK);
    WAIT6; SB; BARR; SB;
    COMPUTE(0, bA);
    BARR; SB;
    STAGEA(0, (ks + 2) * BK);
    LOADB(bA, (ks + 2) * BK);
    WAIT6; SB; BARR; SB;
    COMPUTE(4608, bB);
    BARR; SB;
  }
  STAGEA(4608, (NK - 1) * BK);
  LOADB(bB, (NK - 1) * BK);
  WAIT6; SB; BARR; SB;
  COMPUTE(0, bA);
  WAITZ; SB; BARR; SB;
  COMPUTE(4608, bB);
  BARR; SB;                      // protect epilogue LDS reuse
#undef STAGEA
#undef LOADB
#undef COMPUTE
#undef WAIT6
#undef WAITZ

  // ---- epilogue: per-wave LDS transpose -> bias(+gelu) -> coalesced 16B stores
  float* eps = (float*)lds + w * (16 * 68);
  const float* bp = bias + (size_t)e * N + (size_t)colb * 128 + wn * 64 + (l & 7) * 8;
  float bv[8];
  #pragma unroll
  for (int jj = 0; jj < 8; ++jj) bv[jj] = bp[jj];
  #pragma unroll
  for (int fm = 0; fm < 4; ++fm) {
    #pragma unroll
    for (int fn = 0; fn < 4; ++fn)
      #pragma unroll
      for (int q = 0; q < 4; ++q)
        eps[((l >> 4) * 4 + q) * 68 + fn * 16 + (l & 15)] = acc[fm][fn][q];
    #pragma unroll
    for (int half = 0; half < 2; ++half) {
      int row = (l >> 3) + 8 * half;
      int r = rowb * BM + wm * 64 + fm * 16 + row;
      if (r < cnt) {
        const float* rp = eps + row * 68 + (l & 7) * 8;
        union { bf16 h[8]; uint4 u; } pk;
        #pragma unroll
        for (int jj = 0; jj < 8; ++jj) {
          float v = rp[jj] + bv[jj];
          if (GELU) {
            float u = 0.7978845608028654f * (v + 0.044715f * v * v * v);
            float th = 1.f - 2.f / (__expf(2.f * u) + 1.f);
            v = 0.5f * v * (1.f + th);
          }
          pk.h[jj] = __float2bfloat16(v);
        }
        *(uint4*)(Outb + (size_t)(off + r) * N + (size_t)colb * 128 + wn * 64 + (l & 7) * 8) = pk.u;
      }
    }
    BARR;
  }
#undef SB
#undef BARR
}

// ---------------------------------------------------------------- combine
// Vectorized: ushort4 (8B) loads -> 512B wave segments; float4 stores.
__global__ void combine_kernel(const bf16* __restrict__ z, const float* __restrict__ gates,
                               const int* __restrict__ pos, float* __restrict__ y) {
  int gt = blockIdx.x * 256 + threadIdx.x;
  int tok = gt >> 6, l = gt & 63;
  if (tok >= B_TOK) return;
  const ushort4* z1 = (const ushort4*)(z + (size_t)pos[2 * tok] * D_OUT);
  const ushort4* z2 = (const ushort4*)(z + (size_t)pos[2 * tok + 1] * D_OUT);
  float g1 = gates[2 * tok], g2 = gates[2 * tok + 1];
  float a[12], b[12];
  float m1 = -1e30f, m2 = -1e30f;
  #pragma unroll
  for (int i = 0; i < 3; ++i) {
    ushort4 u1 = z1[l + i * 64];
    ushort4 u2 = z2[l + i * 64];
    unsigned s1v[4] = {u1.x, u1.y, u1.z, u1.w};
    unsigned s2v[4] = {u2.x, u2.y, u2.z, u2.w};
    #pragma unroll
    for (int j = 0; j < 4; ++j) {
      union { unsigned u; float f; } c1, c2;
      c1.u = s1v[j] << 16; c2.u = s2v[j] << 16;
      a[i * 4 + j] = c1.f; b[i * 4 + j] = c2.f;
      m1 = fmaxf(m1, c1.f); m2 = fmaxf(m2, c2.f);
    }
  }
  #pragma unroll
  for (int d = 1; d < 64; d <<= 1) {
    m1 = fmaxf(m1, __shfl_xor(m1, d));
    m2 = fmaxf(m2, __shfl_xor(m2, d));
  }
  float s1 = 0.f, s2 = 0.f;
  #pragma unroll
  for (int i = 0; i < 12; ++i) { s1 += __expf(a[i] - m1); s2 += __expf(b[i] - m2); }
  #pragma unroll
  for (int d = 1; d < 64; d <<= 1) { s1 += __shfl_xor(s1, d); s2 += __shfl_xor(s2, d); }
  float c1 = g1 / s1, c2 = g2 / s2;
  float4* yo = (float4*)(y + (size_t)tok * D_OUT);
  #pragma unroll
  for (int i = 0; i < 3; ++i) {
    float4 o;
    float* op = (float*)&o;
    #pragma unroll
    for (int j = 0; j < 4; ++j) {
      float cmb = c1 * __expf(a[i * 4 + j] - m1) + c2 * __expf(b[i * 4 + j] - m2);
      op[j] = logf(cmb == 0.f ? 2.2204460492503131e-16f : cmb);
    }
    yo[l + i * 64] = o;
  }
}

// ---------------------------------------------------------------- launch
extern "C" void kernel_launch(void* const* d_in, const int* in_sizes, int n_in,
                              void* d_out, int out_size, void* d_ws, size_t ws_size,
                              hipStream_t stream) {
  const float* x  = (const float*)d_in[0];
  const float* wg = (const float*)d_in[1];
  const float* W1 = (const float*)d_in[2];
  const float* b1 = (const float*)d_in[3];
  const float* W2 = (const float*)d_in[4];
  const float* b2 = (const float*)d_in[5];
  float* out = (float*)d_out;

  char* ws = (char*)d_ws;
  int*   cnt_off = (int*)(ws + 0);                // [16]: counts then offsets
  float* gates   = (float*)(ws + 256);            // 4096*2 f32
  int*   tidx    = (int*)(ws + 256 + 32768);
  int*   pos     = (int*)(ws + 256 + 65536);
  int*   row_ids = (int*)(ws + 256 + 98304);
  int*   tmap    = (int*)(ws + 256 + 131072);     // [2*MAXT]
  const size_t base = 262144;
  bf16* x_bf = (bf16*)(ws + base);                        //  6,291,456 B
  bf16* W1t  = (bf16*)(ws + base + 6291456);              // 25,165,824 B
  bf16* W2t  = (bf16*)(ws + base + 31457280);             // 25,165,824 B
  bf16* h_bf = (bf16*)(ws + base + 56623104);             // 33,554,432 B
  bf16* z_bf = (bf16*)(ws + base);                        // aliases x_bf/W1t (dead by GEMM2)

  prep_kernel<<<dim3(4096), 256, 0, stream>>>(x, wg, W1, W1t, x_bf, gates, tidx);
  finalize_kernel<<<dim3(1), 256, 0, stream>>>(tidx, gates, cnt_off, row_ids, pos, tmap,
                                               out + (size_t)B_TOK * D_OUT);
  // GEMM1 (+ W2 transpose fused on extra grid rows: 48 x 16 = 768 blocks)
  gemm_bk32<D_IN, true, true, true><<<dim3(D_H / 128, MAXT + 48), 256, 0, stream>>>(
      x_bf, W1t, b1, h_bf, row_ids, cnt_off, tmap, D_H, W2, W2t);
  gemm_directb<D_H, false><<<dim3(D_OUT / 128, MAXT), 256, 0, stream>>>(
      h_bf, W2t, b2, z_bf, cnt_off, tmap, D_OUT);
  combine_kernel<<<dim3(1024), 256, 0, stream>>>(z_bf, gates, pos, out);
}

// Round 18
// 161.875 us; speedup vs baseline: 1.1167x; 1.1167x over previous
//
#include <hip/hip_runtime.h>
#include <hip/hip_bf16.h>
#include <math.h>

typedef __hip_bfloat16 bf16;
typedef short v8s __attribute__((ext_vector_type(8)));
typedef float v4f __attribute__((ext_vector_type(4)));

#define B_TOK 4096
#define E_EXP 8
#define D_IN  768
#define D_H   2048
#define D_OUT 768
#define MAXT  72      // max M-tiles of 128 over all experts (64 + 7 skew, padded)
#define NTY   48      // W2T grid rows in GEMM1 launch (48 x 16 = 768 transpose blocks)

// ---------------------------------------------------------------- helpers
__device__ __forceinline__ void gl_lds16(const bf16* g, bf16* l) {
  __builtin_amdgcn_global_load_lds(
      (const __attribute__((address_space(1))) unsigned int*)g,
      (__attribute__((address_space(3))) unsigned int*)l, 16, 0, 0);
}

// 64x64 LDS tile transpose (R10-verified swizzle; 256B-segment reads,
// 64B-cluster writes).  tile rows = 72 bf16 (144B).
__device__ __forceinline__ void transpose_tile64(
    const float* __restrict__ W, bf16* __restrict__ Wt,
    int K, int N, int e, int k0, int n0, int t, bf16 (*tile)[72]) {
  const int w = t >> 6, l = t & 63;
  const float* Wp = W + (size_t)e * K * N;
  #pragma unroll
  for (int p = 0; p < 4; ++p) {
    int k_loc = w * 16 + p * 4 + (l >> 4);
    int nn = (l & 15) * 4;
    float4 v = *(const float4*)(Wp + (size_t)(k0 + k_loc) * N + n0 + nn);
    float vv[4] = {v.x, v.y, v.z, v.w};
    #pragma unroll
    for (int i = 0; i < 4; ++i) {
      int n_loc = nn + i;
      int phys = (k_loc >> 3) ^ ((n_loc >> 2) & 7);
      tile[n_loc][phys * 8 + (k_loc & 7)] = __float2bfloat16(vv[i]);
    }
  }
  __syncthreads();
  bf16* Wtp = Wt + (size_t)e * N * K;
  const int nsub = l >> 2;
  #pragma unroll
  for (int p2 = 0; p2 < 2; ++p2) {
    int c = (l & 3) + p2 * 4;
    int n_loc = w * 16 + nsub;
    int phys = c ^ ((n_loc >> 2) & 7);
    v8s val = *(const v8s*)&tile[n_loc][phys * 8];
    *(v8s*)(Wtp + (size_t)(n0 + n_loc) * K + k0 + c * 8) = val;
  }
}

// ---------------------------------------------------------------- prep1:
// blocks [0,3072): W1 transpose; [3072,4096): gate + x->bf16.
__global__ __launch_bounds__(256)
void prep_kernel(const float* __restrict__ x, const float* __restrict__ wg,
                 const float* __restrict__ W1, bf16* __restrict__ W1t,
                 bf16* __restrict__ xb, float* __restrict__ gates,
                 int* __restrict__ tidx) {
  __shared__ bf16 tile[64][72];
  const int b = blockIdx.x;
  const int t = threadIdx.x;
  if (b < 3072) {
    int e = b / 384, rem = b % 384;
    int kb = rem % 12, nb = rem / 12;        // K=768: 12 k-tiles; N=2048: 32 n-tiles
    transpose_tile64(W1, W1t, D_IN, D_H, e, kb * 64, nb * 64, t, tile);
  } else {
    int gt = (b - 3072) * 256 + t;
    int tok = gt >> 6, l = gt & 63;
    const float* xr = x + (size_t)tok * D_IN;
    bf16* xbr = xb + (size_t)tok * D_IN;
    float acc[8] = {0.f,0.f,0.f,0.f,0.f,0.f,0.f,0.f};
    #pragma unroll
    for (int i = 0; i < 3; ++i) {
      int k0 = i * 256 + l * 4;
      float4 v = *(const float4*)(xr + k0);
      union { bf16 h[4]; uint2 u; } pk;
      pk.h[0] = __float2bfloat16(v.x); pk.h[1] = __float2bfloat16(v.y);
      pk.h[2] = __float2bfloat16(v.z); pk.h[3] = __float2bfloat16(v.w);
      *(uint2*)(xbr + k0) = pk.u;
      float xv[4] = {v.x, v.y, v.z, v.w};
      #pragma unroll
      for (int j = 0; j < 4; ++j) {
        const float* wr = wg + (size_t)(k0 + j) * 8;
        float4 w0 = *(const float4*)wr;
        float4 w1 = *(const float4*)(wr + 4);
        acc[0] += xv[j] * w0.x; acc[1] += xv[j] * w0.y;
        acc[2] += xv[j] * w0.z; acc[3] += xv[j] * w0.w;
        acc[4] += xv[j] * w1.x; acc[5] += xv[j] * w1.y;
        acc[6] += xv[j] * w1.z; acc[7] += xv[j] * w1.w;
      }
    }
    #pragma unroll
    for (int d = 1; d < 64; d <<= 1)
      #pragma unroll
      for (int e2 = 0; e2 < 8; ++e2) acc[e2] += __shfl_xor(acc[e2], d);
    if (l == 0) {
      int i1 = 0; float v1 = acc[0];
      #pragma unroll
      for (int e2 = 1; e2 < 8; ++e2) if (acc[e2] > v1) { v1 = acc[e2]; i1 = e2; }
      int i2 = -1; float v2 = -1e30f;
      #pragma unroll
      for (int e2 = 0; e2 < 8; ++e2) if (e2 != i1 && acc[e2] > v2) { v2 = acc[e2]; i2 = e2; }
      float ex = __expf(v2 - v1);
      float g1 = 1.f / (1.f + ex), g2 = ex / (1.f + ex);
      gates[2 * tok] = g1; gates[2 * tok + 1] = g2;
      tidx[2 * tok] = i1;  tidx[2 * tok + 1] = i2;
    }
  }
}

// ---------------------------------------------- single-block: histogram + scan +
// slot assignment + counts/offsets + tile map + aux loss.  256 threads.
__global__ void finalize_kernel(const int* __restrict__ tidx, const float* __restrict__ gates,
                                int* __restrict__ cnt_off, int* __restrict__ row_ids,
                                int* __restrict__ pos, int* __restrict__ tmap,
                                float* __restrict__ loss_out) {
  __shared__ int   hcnt[256][9];
  __shared__ float himp[256][9];
  __shared__ int   tot[8], off[8];
  __shared__ float itot[8];
  int t = threadIdx.x;
  #pragma unroll
  for (int e = 0; e < 8; ++e) { hcnt[t][e] = 0; himp[t][e] = 0.f; }
  __syncthreads();
  for (int i = 0; i < 32; ++i) {
    int idx = t * 32 + i;
    int e = tidx[idx];
    hcnt[t][e] += 1;
    himp[t][e] += gates[idx];
  }
  __syncthreads();
  if (t < 8) {
    int run = 0; float s = 0.f;
    for (int j = 0; j < 256; ++j) {
      int c = hcnt[j][t];
      hcnt[j][t] = run;
      run += c;
      s += himp[j][t];
    }
    tot[t] = run; itot[t] = s;
  }
  __syncthreads();
  if (t == 0) {
    int o = 0;
    float mi = 0.f, ml = 0.f;
    for (int e = 0; e < 8; ++e) {
      off[e] = o; o += tot[e];
      cnt_off[e] = tot[e]; cnt_off[8 + e] = off[e];
      mi += itot[e]; ml += (float)tot[e];
    }
    mi *= 0.125f; ml *= 0.125f;
    float vi = 0.f, vl = 0.f;
    for (int e = 0; e < 8; ++e) {
      float d = itot[e] - mi;        vi += d * d;
      float d2 = (float)tot[e] - ml; vl += d2 * d2;
    }
    vi /= 7.f; vl /= 7.f;
    *loss_out = 0.01f * (vi / (mi * mi + 1e-10f) + vl / (ml * ml + 1e-10f));
    int nt = 0;
    for (int e = 0; e < 8; ++e)
      for (int tt = 0; tt < (tot[e] + 127) >> 7; ++tt) {
        tmap[nt] = e; tmap[MAXT + nt] = tt; ++nt;
      }
    for (; nt < MAXT; ++nt) tmap[nt] = -1;
  }
  __syncthreads();
  for (int i = 0; i < 32; ++i) {
    int idx = t * 32 + i;
    int e = tidx[idx];
    int slot = off[e] + hcnt[t][e];
    hcnt[t][e] += 1;
    row_ids[slot] = idx >> 1;
    pos[idx] = slot;
  }
}

// ---------------------------------------------------------------- grouped GEMM
// 128x128 tile, BK=32, 256 threads, 2-buffer counted-vmcnt(4), 32 KiB LDS ->
// 4 blocks/CU.  Chunk swizzle p = c ^ ((row>>1)&3) (verified R8-R16).
// DOTRANS: grid rows y < NTY transpose W2 FIRST (dispatch order is y-last for
// larger y -> transpose traffic overlaps the GEMM compute ramp instead of
// forming a serial tail); GEMM rows use ti = y - NTY.
template<int KDIM, bool GATHER, bool GELU, bool DOTRANS>
__global__ __launch_bounds__(256, 4)
void gemm_bk32(const bf16* __restrict__ Ab, const bf16* __restrict__ Wt,
               const float* __restrict__ bias, bf16* __restrict__ Outb,
               const int* __restrict__ row_ids, const int* __restrict__ cnt_off,
               const int* __restrict__ tmap, const int N,
               const float* __restrict__ Wsrc, bf16* __restrict__ Wdst) {
  constexpr int BK = 32, BM = 128, BN = 128;
  constexpr int NK = KDIM / BK;
  static_assert(NK % 2 == 0 && NK >= 4, "NK even, >=4");
  __shared__ __align__(16) bf16 lds[2][(BM + BN) * BK];   // 2 x 16 KiB
  const int t = (int)threadIdx.x, w = t >> 6, l = t & 63;
  if (DOTRANS && blockIdx.y < NTY) {
    int tid = blockIdx.y * gridDim.x + blockIdx.x;             // 0..767
    int e = tid / 96, r = tid % 96;
    int kb = r % 8, nb = r / 8;                                // 8 x 256k, 12 x 64n
    bf16 (*tile)[72] = (bf16(*)[72])&lds[0][0];
    #pragma unroll 1
    for (int sub = 0; sub < 4; ++sub) {
      transpose_tile64(Wsrc, Wdst, D_H, D_OUT, e, kb * 256 + sub * 64, nb * 64, t, tile);
      __syncthreads();
    }
    return;
  }
  const int ti = DOTRANS ? ((int)blockIdx.y - NTY) : (int)blockIdx.y;
  const int e = tmap[ti];
  if (e < 0) return;
  const int rowb = tmap[MAXT + ti];
  const int cnt = cnt_off[e];
  const int off = cnt_off[8 + e];
  const int colb = blockIdx.x;
  const int cs = (l & 3) ^ ((l >> 3) & 3);   // pre-swizzled source chunk (of 4)
  const bf16* gA[2];
  const bf16* gB[2];
  #pragma unroll
  for (int it = 0; it < 2; ++it) {
    int rt = (it * 4 + w) * 16 + (l >> 2);   // slab*16 + row-in-slab
    int r = rowb * BM + rt;
    int rc = r < cnt ? r : cnt - 1;
    long arow = GATHER ? (long)row_ids[off + rc] : (long)(off + rc);
    gA[it] = Ab + arow * (long)KDIM + cs * 8;
    gB[it] = Wt + ((size_t)e * N + (size_t)colb * BN + rt) * KDIM + cs * 8;
  }
  v4f acc[4][4] = {};
  const int wm = w >> 1, wn = w & 1;

#define STAGE(b, k0) do {                                                   \
    _Pragma("unroll")                                                       \
    for (int it = 0; it < 2; ++it)                                          \
      gl_lds16(gA[it] + (k0), &lds[b][(it * 4 + w) * 512]);                 \
    _Pragma("unroll")                                                       \
    for (int it = 0; it < 2; ++it)                                          \
      gl_lds16(gB[it] + (k0), &lds[b][BM * BK + (it * 4 + w) * 512]);       \
  } while (0)

#define COMPUTE(b) do {                                                     \
    __builtin_amdgcn_s_setprio(1);                                          \
    v8s af[4], bfr[4];                                                      \
    const int p = (l >> 4) ^ ((l >> 1) & 3);                                \
    _Pragma("unroll")                                                       \
    for (int fm = 0; fm < 4; ++fm) {                                        \
      int row = wm * 64 + fm * 16 + (l & 15);                               \
      af[fm] = *(const v8s*)(&lds[b][0] + row * BK + p * 8);                \
    }                                                                       \
    _Pragma("unroll")                                                       \
    for (int fn = 0; fn < 4; ++fn) {                                        \
      int row = wn * 64 + fn * 16 + (l & 15);                               \
      bfr[fn] = *(const v8s*)(&lds[b][BM * BK] + row * BK + p * 8);         \
    }                                                                       \
    _Pragma("unroll")                                                       \
    for (int fm = 0; fm < 4; ++fm)                                          \
      _Pragma("unroll")                                                     \
      for (int fn = 0; fn < 4; ++fn)                                        \
        acc[fm][fn] = __builtin_amdgcn_mfma_f32_16x16x32_bf16(af[fm], bfr[fn], acc[fm][fn], 0, 0, 0); \
    __builtin_amdgcn_s_setprio(0);                                          \
  } while (0)

#define SB    __builtin_amdgcn_sched_barrier(0)
#define BARR  __builtin_amdgcn_s_barrier()
#define WAIT4 asm volatile("s_waitcnt vmcnt(4)" ::: "memory")
#define WAITZ asm volatile("s_waitcnt vmcnt(0)" ::: "memory")

  STAGE(0, 0);
  #pragma unroll 1
  for (int ks = 0; ks < NK - 2; ks += 2) {
    STAGE(1, (ks + 1) * BK);
    WAIT4; SB; BARR; SB;
    COMPUTE(0);
    BARR; SB;
    STAGE(0, (ks + 2) * BK);
    WAIT4; SB; BARR; SB;
    COMPUTE(1);
    BARR; SB;
  }
  STAGE(1, (NK - 1) * BK);
  WAIT4; SB; BARR; SB;
  COMPUTE(0);
  WAITZ; SB; BARR; SB;
  COMPUTE(1);
  BARR; SB;                      // protect epilogue LDS reuse
#undef STAGE
#undef COMPUTE
#undef WAIT4
#undef WAITZ

  // ---- epilogue: per-wave LDS transpose -> bias(+gelu) -> coalesced 16B stores
  float* eps = (float*)(&lds[0][0]) + w * (16 * 68);
  const float* bp = bias + (size_t)e * N + (size_t)colb * BN + wn * 64 + (l & 7) * 8;
  float bv[8];
  #pragma unroll
  for (int jj = 0; jj < 8; ++jj) bv[jj] = bp[jj];
  #pragma unroll
  for (int fm = 0; fm < 4; ++fm) {
    #pragma unroll
    for (int fn = 0; fn < 4; ++fn)
      #pragma unroll
      for (int q = 0; q < 4; ++q)
        eps[((l >> 4) * 4 + q) * 68 + fn * 16 + (l & 15)] = acc[fm][fn][q];
    #pragma unroll
    for (int half = 0; half < 2; ++half) {
      int row = (l >> 3) + 8 * half;
      int r = rowb * BM + wm * 64 + fm * 16 + row;
      if (r < cnt) {
        const float* rp = eps + row * 68 + (l & 7) * 8;
        union { bf16 h[8]; uint4 u; } pk;
        #pragma unroll
        for (int jj = 0; jj < 8; ++jj) {
          float v = rp[jj] + bv[jj];
          if (GELU) {
            float u = 0.7978845608028654f * (v + 0.044715f * v * v * v);
            float th = 1.f - 2.f / (__expf(2.f * u) + 1.f);   // tanh(u)
            v = 0.5f * v * (1.f + th);
          }
          pk.h[jj] = __float2bfloat16(v);
        }
        *(uint4*)(Outb + (size_t)(off + r) * N + (size_t)colb * BN + wn * 64 + (l & 7) * 8) = pk.u;
      }
    }
  }
#undef SB
#undef BARR
}

// ---------------------------------------------------------------- combine
// Vectorized: ushort4 (8B) loads -> 512B wave segments; float4 stores.
__global__ void combine_kernel(const bf16* __restrict__ z, const float* __restrict__ gates,
                               const int* __restrict__ pos, float* __restrict__ y) {
  int gt = blockIdx.x * 256 + threadIdx.x;
  int tok = gt >> 6, l = gt & 63;
  if (tok >= B_TOK) return;
  const ushort4* z1 = (const ushort4*)(z + (size_t)pos[2 * tok] * D_OUT);
  const ushort4* z2 = (const ushort4*)(z + (size_t)pos[2 * tok + 1] * D_OUT);
  float g1 = gates[2 * tok], g2 = gates[2 * tok + 1];
  float a[12], b[12];
  float m1 = -1e30f, m2 = -1e30f;
  #pragma unroll
  for (int i = 0; i < 3; ++i) {
    ushort4 u1 = z1[l + i * 64];
    ushort4 u2 = z2[l + i * 64];
    unsigned s1v[4] = {u1.x, u1.y, u1.z, u1.w};
    unsigned s2v[4] = {u2.x, u2.y, u2.z, u2.w};
    #pragma unroll
    for (int j = 0; j < 4; ++j) {
      union { unsigned u; float f; } c1, c2;
      c1.u = s1v[j] << 16; c2.u = s2v[j] << 16;
      a[i * 4 + j] = c1.f; b[i * 4 + j] = c2.f;
      m1 = fmaxf(m1, c1.f); m2 = fmaxf(m2, c2.f);
    }
  }
  #pragma unroll
  for (int d = 1; d < 64; d <<= 1) {
    m1 = fmaxf(m1, __shfl_xor(m1, d));
    m2 = fmaxf(m2, __shfl_xor(m2, d));
  }
  float s1 = 0.f, s2 = 0.f;
  #pragma unroll
  for (int i = 0; i < 12; ++i) { s1 += __expf(a[i] - m1); s2 += __expf(b[i] - m2); }
  #pragma unroll
  for (int d = 1; d < 64; d <<= 1) { s1 += __shfl_xor(s1, d); s2 += __shfl_xor(s2, d); }
  float c1 = g1 / s1, c2 = g2 / s2;
  float4* yo = (float4*)(y + (size_t)tok * D_OUT);
  #pragma unroll
  for (int i = 0; i < 3; ++i) {
    float4 o;
    float* op = (float*)&o;
    #pragma unroll
    for (int j = 0; j < 4; ++j) {
      float cmb = c1 * __expf(a[i * 4 + j] - m1) + c2 * __expf(b[i * 4 + j] - m2);
      op[j] = logf(cmb == 0.f ? 2.2204460492503131e-16f : cmb);
    }
    yo[l + i * 64] = o;
  }
}

// ---------------------------------------------------------------- launch
extern "C" void kernel_launch(void* const* d_in, const int* in_sizes, int n_in,
                              void* d_out, int out_size, void* d_ws, size_t ws_size,
                              hipStream_t stream) {
  const float* x  = (const float*)d_in[0];
  const float* wg = (const float*)d_in[1];
  const float* W1 = (const float*)d_in[2];
  const float* b1 = (const float*)d_in[3];
  const float* W2 = (const float*)d_in[4];
  const float* b2 = (const float*)d_in[5];
  float* out = (float*)d_out;

  char* ws = (char*)d_ws;
  int*   cnt_off = (int*)(ws + 0);                // [16]: counts then offsets
  float* gates   = (float*)(ws + 256);            // 4096*2 f32
  int*   tidx    = (int*)(ws + 256 + 32768);
  int*   pos     = (int*)(ws + 256 + 65536);
  int*   row_ids = (int*)(ws + 256 + 98304);
  int*   tmap    = (int*)(ws + 256 + 131072);     // [2*MAXT]
  const size_t base = 262144;
  bf16* x_bf = (bf16*)(ws + base);                        //  6,291,456 B
  bf16* W1t  = (bf16*)(ws + base + 6291456);              // 25,165,824 B
  bf16* W2t  = (bf16*)(ws + base + 31457280);             // 25,165,824 B
  bf16* h_bf = (bf16*)(ws + base + 56623104);             // 33,554,432 B
  bf16* z_bf = (bf16*)(ws + base);                        // aliases x_bf/W1t (dead by GEMM2)

  prep_kernel<<<dim3(4096), 256, 0, stream>>>(x, wg, W1, W1t, x_bf, gates, tidx);
  finalize_kernel<<<dim3(1), 256, 0, stream>>>(tidx, gates, cnt_off, row_ids, pos, tmap,
                                               out + (size_t)B_TOK * D_OUT);
  // GEMM1 (+ W2 transpose on y<NTY rows -> overlaps GEMM ramp, no tail)
  gemm_bk32<D_IN, true, true, true><<<dim3(D_H / 128, NTY + MAXT), 256, 0, stream>>>(
      x_bf, W1t, b1, h_bf, row_ids, cnt_off, tmap, D_H, W2, W2t);
  gemm_bk32<D_H, false, false, false><<<dim3(D_OUT / 128, MAXT), 256, 0, stream>>>(
      h_bf, W2t, b2, z_bf, row_ids, cnt_off, tmap, D_OUT, nullptr, nullptr);
  combine_kernel<<<dim3(1024), 256, 0, stream>>>(z_bf, gates, pos, out);
}

// Round 19
// 157.289 us; speedup vs baseline: 1.1492x; 1.0292x over previous
//
#include <hip/hip_runtime.h>
#include <hip/hip_bf16.h>
#include <math.h>

typedef __hip_bfloat16 bf16;
typedef short v8s __attribute__((ext_vector_type(8)));
typedef float v4f __attribute__((ext_vector_type(4)));

#define B_TOK 4096
#define E_EXP 8
#define D_IN  768
#define D_H   2048
#define D_OUT 768
#define MAXT  72      // max M-tiles of 128 over all experts (64 + 7 skew, padded)

// ---------------------------------------------------------------- helpers
__device__ __forceinline__ void gl_lds16(const bf16* g, bf16* l) {
  __builtin_amdgcn_global_load_lds(
      (const __attribute__((address_space(1))) unsigned int*)g,
      (__attribute__((address_space(3))) unsigned int*)l, 16, 0, 0);
}

// 64x64 LDS tile transpose (R10-verified swizzle; 256B-segment reads,
// 64B-cluster writes).  tile rows = 72 bf16 (144B).
__device__ __forceinline__ void transpose_tile64(
    const float* __restrict__ W, bf16* __restrict__ Wt,
    int K, int N, int e, int k0, int n0, int t, bf16 (*tile)[72]) {
  const int w = t >> 6, l = t & 63;
  const float* Wp = W + (size_t)e * K * N;
  #pragma unroll
  for (int p = 0; p < 4; ++p) {
    int k_loc = w * 16 + p * 4 + (l >> 4);
    int nn = (l & 15) * 4;
    float4 v = *(const float4*)(Wp + (size_t)(k0 + k_loc) * N + n0 + nn);
    float vv[4] = {v.x, v.y, v.z, v.w};
    #pragma unroll
    for (int i = 0; i < 4; ++i) {
      int n_loc = nn + i;
      int phys = (k_loc >> 3) ^ ((n_loc >> 2) & 7);
      tile[n_loc][phys * 8 + (k_loc & 7)] = __float2bfloat16(vv[i]);
    }
  }
  __syncthreads();
  bf16* Wtp = Wt + (size_t)e * N * K;
  const int nsub = l >> 2;
  #pragma unroll
  for (int p2 = 0; p2 < 2; ++p2) {
    int c = (l & 3) + p2 * 4;
    int n_loc = w * 16 + nsub;
    int phys = c ^ ((n_loc >> 2) & 7);
    v8s val = *(const v8s*)&tile[n_loc][phys * 8];
    *(v8s*)(Wtp + (size_t)(n0 + n_loc) * K + k0 + c * 8) = val;
  }
}

// ---------------------------------------------------------------- prep1:
// blocks [0,3072): W1 transpose; [3072,4096): gate + x->bf16.
__global__ __launch_bounds__(256)
void prep_kernel(const float* __restrict__ x, const float* __restrict__ wg,
                 const float* __restrict__ W1, bf16* __restrict__ W1t,
                 bf16* __restrict__ xb, float* __restrict__ gates,
                 int* __restrict__ tidx) {
  __shared__ bf16 tile[64][72];
  const int b = blockIdx.x;
  const int t = threadIdx.x;
  if (b < 3072) {
    int e = b / 384, rem = b % 384;
    int kb = rem % 12, nb = rem / 12;        // K=768: 12 k-tiles; N=2048: 32 n-tiles
    transpose_tile64(W1, W1t, D_IN, D_H, e, kb * 64, nb * 64, t, tile);
  } else {
    int gt = (b - 3072) * 256 + t;
    int tok = gt >> 6, l = gt & 63;
    const float* xr = x + (size_t)tok * D_IN;
    bf16* xbr = xb + (size_t)tok * D_IN;
    float acc[8] = {0.f,0.f,0.f,0.f,0.f,0.f,0.f,0.f};
    #pragma unroll
    for (int i = 0; i < 3; ++i) {
      int k0 = i * 256 + l * 4;
      float4 v = *(const float4*)(xr + k0);
      union { bf16 h[4]; uint2 u; } pk;
      pk.h[0] = __float2bfloat16(v.x); pk.h[1] = __float2bfloat16(v.y);
      pk.h[2] = __float2bfloat16(v.z); pk.h[3] = __float2bfloat16(v.w);
      *(uint2*)(xbr + k0) = pk.u;
      float xv[4] = {v.x, v.y, v.z, v.w};
      #pragma unroll
      for (int j = 0; j < 4; ++j) {
        const float* wr = wg + (size_t)(k0 + j) * 8;
        float4 w0 = *(const float4*)wr;
        float4 w1 = *(const float4*)(wr + 4);
        acc[0] += xv[j] * w0.x; acc[1] += xv[j] * w0.y;
        acc[2] += xv[j] * w0.z; acc[3] += xv[j] * w0.w;
        acc[4] += xv[j] * w1.x; acc[5] += xv[j] * w1.y;
        acc[6] += xv[j] * w1.z; acc[7] += xv[j] * w1.w;
      }
    }
    #pragma unroll
    for (int d = 1; d < 64; d <<= 1)
      #pragma unroll
      for (int e2 = 0; e2 < 8; ++e2) acc[e2] += __shfl_xor(acc[e2], d);
    if (l == 0) {
      int i1 = 0; float v1 = acc[0];
      #pragma unroll
      for (int e2 = 1; e2 < 8; ++e2) if (acc[e2] > v1) { v1 = acc[e2]; i1 = e2; }
      int i2 = -1; float v2 = -1e30f;
      #pragma unroll
      for (int e2 = 0; e2 < 8; ++e2) if (e2 != i1 && acc[e2] > v2) { v2 = acc[e2]; i2 = e2; }
      float ex = __expf(v2 - v1);
      float g1 = 1.f / (1.f + ex), g2 = ex / (1.f + ex);
      gates[2 * tok] = g1; gates[2 * tok + 1] = g2;
      tidx[2 * tok] = i1;  tidx[2 * tok + 1] = i2;
    }
  }
}

// ---------------------------------------------- single-block: histogram + scan +
// slot assignment + counts/offsets + tile map + aux loss.  256 threads.
__global__ void finalize_kernel(const int* __restrict__ tidx, const float* __restrict__ gates,
                                int* __restrict__ cnt_off, int* __restrict__ row_ids,
                                int* __restrict__ pos, int* __restrict__ tmap,
                                float* __restrict__ loss_out) {
  __shared__ int   hcnt[256][9];
  __shared__ float himp[256][9];
  __shared__ int   tot[8], off[8];
  __shared__ float itot[8];
  int t = threadIdx.x;
  #pragma unroll
  for (int e = 0; e < 8; ++e) { hcnt[t][e] = 0; himp[t][e] = 0.f; }
  __syncthreads();
  for (int i = 0; i < 32; ++i) {
    int idx = t * 32 + i;
    int e = tidx[idx];
    hcnt[t][e] += 1;
    himp[t][e] += gates[idx];
  }
  __syncthreads();
  if (t < 8) {
    int run = 0; float s = 0.f;
    for (int j = 0; j < 256; ++j) {
      int c = hcnt[j][t];
      hcnt[j][t] = run;
      run += c;
      s += himp[j][t];
    }
    tot[t] = run; itot[t] = s;
  }
  __syncthreads();
  if (t == 0) {
    int o = 0;
    float mi = 0.f, ml = 0.f;
    for (int e = 0; e < 8; ++e) {
      off[e] = o; o += tot[e];
      cnt_off[e] = tot[e]; cnt_off[8 + e] = off[e];
      mi += itot[e]; ml += (float)tot[e];
    }
    mi *= 0.125f; ml *= 0.125f;
    float vi = 0.f, vl = 0.f;
    for (int e = 0; e < 8; ++e) {
      float d = itot[e] - mi;        vi += d * d;
      float d2 = (float)tot[e] - ml; vl += d2 * d2;
    }
    vi /= 7.f; vl /= 7.f;
    *loss_out = 0.01f * (vi / (mi * mi + 1e-10f) + vl / (ml * ml + 1e-10f));
    int nt = 0;
    for (int e = 0; e < 8; ++e)
      for (int tt = 0; tt < (tot[e] + 127) >> 7; ++tt) {
        tmap[nt] = e; tmap[MAXT + nt] = tt; ++nt;
      }
    for (; nt < MAXT; ++nt) tmap[nt] = -1;
  }
  __syncthreads();
  for (int i = 0; i < 32; ++i) {
    int idx = t * 32 + i;
    int e = tidx[idx];
    int slot = off[e] + hcnt[t][e];
    hcnt[t][e] += 1;
    row_ids[slot] = idx >> 1;
    pos[idx] = slot;
  }
}

// ---------------------------------------------------------------- grouped GEMM
// 128x128 tile, BK=32, 256 threads, 2-buffer counted-vmcnt(4), 32 KiB LDS ->
// 4 blocks/CU.  Chunk swizzle p = c ^ ((row>>1)&3) (verified R8-R18).
// DOTRANS: extra grid rows (y >= MAXT) transpose W2 (tail rides with GEMM1;
// R18 showed front-loading is worse).
template<int KDIM, bool GATHER, bool GELU, bool DOTRANS>
__global__ __launch_bounds__(256, 4)
void gemm_bk32(const bf16* __restrict__ Ab, const bf16* __restrict__ Wt,
               const float* __restrict__ bias, bf16* __restrict__ Outb,
               const int* __restrict__ row_ids, const int* __restrict__ cnt_off,
               const int* __restrict__ tmap, const int N,
               const float* __restrict__ Wsrc, bf16* __restrict__ Wdst) {
  constexpr int BK = 32, BM = 128, BN = 128;
  constexpr int NK = KDIM / BK;
  static_assert(NK % 2 == 0 && NK >= 4, "NK even, >=4");
  __shared__ __align__(16) bf16 lds[2][(BM + BN) * BK];   // 2 x 16 KiB
  const int t = (int)threadIdx.x, w = t >> 6, l = t & 63;
  if (DOTRANS && blockIdx.y >= MAXT) {
    int tid = (blockIdx.y - MAXT) * gridDim.x + blockIdx.x;   // 0..767
    int e = tid / 96, r = tid % 96;
    int kb = r % 8, nb = r / 8;                                // 8 x 256k, 12 x 64n
    bf16 (*tile)[72] = (bf16(*)[72])&lds[0][0];
    #pragma unroll 1
    for (int sub = 0; sub < 4; ++sub) {
      transpose_tile64(Wsrc, Wdst, D_H, D_OUT, e, kb * 256 + sub * 64, nb * 64, t, tile);
      __syncthreads();
    }
    return;
  }
  const int ti = blockIdx.y;
  const int e = tmap[ti];
  if (e < 0) return;
  const int rowb = tmap[MAXT + ti];
  const int cnt = cnt_off[e];
  const int off = cnt_off[8 + e];
  const int colb = blockIdx.x;
  const int cs = (l & 3) ^ ((l >> 3) & 3);   // pre-swizzled source chunk (of 4)
  const bf16* gA[2];
  const bf16* gB[2];
  #pragma unroll
  for (int it = 0; it < 2; ++it) {
    int rt = (it * 4 + w) * 16 + (l >> 2);   // slab*16 + row-in-slab
    int r = rowb * BM + rt;
    int rc = r < cnt ? r : cnt - 1;
    long arow = GATHER ? (long)row_ids[off + rc] : (long)(off + rc);
    gA[it] = Ab + arow * (long)KDIM + cs * 8;
    gB[it] = Wt + ((size_t)e * N + (size_t)colb * BN + rt) * KDIM + cs * 8;
  }
  v4f acc[4][4] = {};
  const int wm = w >> 1, wn = w & 1;

#define STAGE(b, k0) do {                                                   \
    _Pragma("unroll")                                                       \
    for (int it = 0; it < 2; ++it)                                          \
      gl_lds16(gA[it] + (k0), &lds[b][(it * 4 + w) * 512]);                 \
    _Pragma("unroll")                                                       \
    for (int it = 0; it < 2; ++it)                                          \
      gl_lds16(gB[it] + (k0), &lds[b][BM * BK + (it * 4 + w) * 512]);       \
  } while (0)

#define COMPUTE(b) do {                                                     \
    __builtin_amdgcn_s_setprio(1);                                          \
    v8s af[4], bfr[4];                                                      \
    const int p = (l >> 4) ^ ((l >> 1) & 3);                                \
    _Pragma("unroll")                                                       \
    for (int fm = 0; fm < 4; ++fm) {                                        \
      int row = wm * 64 + fm * 16 + (l & 15);                               \
      af[fm] = *(const v8s*)(&lds[b][0] + row * BK + p * 8);                \
    }                                                                       \
    _Pragma("unroll")                                                       \
    for (int fn = 0; fn < 4; ++fn) {                                        \
      int row = wn * 64 + fn * 16 + (l & 15);                               \
      bfr[fn] = *(const v8s*)(&lds[b][BM * BK] + row * BK + p * 8);         \
    }                                                                       \
    _Pragma("unroll")                                                       \
    for (int fm = 0; fm < 4; ++fm)                                          \
      _Pragma("unroll")                                                     \
      for (int fn = 0; fn < 4; ++fn)                                        \
        acc[fm][fn] = __builtin_amdgcn_mfma_f32_16x16x32_bf16(af[fm], bfr[fn], acc[fm][fn], 0, 0, 0); \
    __builtin_amdgcn_s_setprio(0);                                          \
  } while (0)

#define SB    __builtin_amdgcn_sched_barrier(0)
#define BARR  __builtin_amdgcn_s_barrier()
#define WAIT4 asm volatile("s_waitcnt vmcnt(4)" ::: "memory")
#define WAITZ asm volatile("s_waitcnt vmcnt(0)" ::: "memory")

  STAGE(0, 0);
  #pragma unroll 1
  for (int ks = 0; ks < NK - 2; ks += 2) {
    STAGE(1, (ks + 1) * BK);
    WAIT4; SB; BARR; SB;
    COMPUTE(0);
    BARR; SB;
    STAGE(0, (ks + 2) * BK);
    WAIT4; SB; BARR; SB;
    COMPUTE(1);
    BARR; SB;
  }
  STAGE(1, (NK - 1) * BK);
  WAIT4; SB; BARR; SB;
  COMPUTE(0);
  WAITZ; SB; BARR; SB;
  COMPUTE(1);
  BARR; SB;                      // protect epilogue LDS reuse
#undef STAGE
#undef COMPUTE
#undef WAIT4
#undef WAITZ

  // ---- epilogue: per-wave LDS transpose -> bias(+gelu) -> coalesced 16B stores
  float* eps = (float*)(&lds[0][0]) + w * (16 * 68);
  const float* bp = bias + (size_t)e * N + (size_t)colb * BN + wn * 64 + (l & 7) * 8;
  float bv[8];
  #pragma unroll
  for (int jj = 0; jj < 8; ++jj) bv[jj] = bp[jj];
  #pragma unroll
  for (int fm = 0; fm < 4; ++fm) {
    #pragma unroll
    for (int fn = 0; fn < 4; ++fn)
      #pragma unroll
      for (int q = 0; q < 4; ++q)
        eps[((l >> 4) * 4 + q) * 68 + fn * 16 + (l & 15)] = acc[fm][fn][q];
    #pragma unroll
    for (int half = 0; half < 2; ++half) {
      int row = (l >> 3) + 8 * half;
      int r = rowb * BM + wm * 64 + fm * 16 + row;
      if (r < cnt) {
        const float* rp = eps + row * 68 + (l & 7) * 8;
        union { bf16 h[8]; uint4 u; } pk;
        #pragma unroll
        for (int jj = 0; jj < 8; ++jj) {
          float v = rp[jj] + bv[jj];
          if (GELU) {
            float u = 0.7978845608028654f * (v + 0.044715f * v * v * v);
            float th = 1.f - 2.f / (__expf(2.f * u) + 1.f);   // tanh(u)
            v = 0.5f * v * (1.f + th);
          }
          pk.h[jj] = __float2bfloat16(v);
        }
        *(uint4*)(Outb + (size_t)(off + r) * N + (size_t)colb * BN + wn * 64 + (l & 7) * 8) = pk.u;
      }
    }
  }
#undef SB
#undef BARR
}

// ---------------------------------------------------------------- combine
// Vectorized: ushort4 (8B) loads -> 512B wave segments; float4 stores.
__global__ void combine_kernel(const bf16* __restrict__ z, const float* __restrict__ gates,
                               const int* __restrict__ pos, float* __restrict__ y) {
  int gt = blockIdx.x * 256 + threadIdx.x;
  int tok = gt >> 6, l = gt & 63;
  if (tok >= B_TOK) return;
  const ushort4* z1 = (const ushort4*)(z + (size_t)pos[2 * tok] * D_OUT);
  const ushort4* z2 = (const ushort4*)(z + (size_t)pos[2 * tok + 1] * D_OUT);
  float g1 = gates[2 * tok], g2 = gates[2 * tok + 1];
  float a[12], b[12];
  float m1 = -1e30f, m2 = -1e30f;
  #pragma unroll
  for (int i = 0; i < 3; ++i) {
    ushort4 u1 = z1[l + i * 64];
    ushort4 u2 = z2[l + i * 64];
    unsigned s1v[4] = {u1.x, u1.y, u1.z, u1.w};
    unsigned s2v[4] = {u2.x, u2.y, u2.z, u2.w};
    #pragma unroll
    for (int j = 0; j < 4; ++j) {
      union { unsigned u; float f; } c1, c2;
      c1.u = s1v[j] << 16; c2.u = s2v[j] << 16;
      a[i * 4 + j] = c1.f; b[i * 4 + j] = c2.f;
      m1 = fmaxf(m1, c1.f); m2 = fmaxf(m2, c2.f);
    }
  }
  #pragma unroll
  for (int d = 1; d < 64; d <<= 1) {
    m1 = fmaxf(m1, __shfl_xor(m1, d));
    m2 = fmaxf(m2, __shfl_xor(m2, d));
  }
  float s1 = 0.f, s2 = 0.f;
  #pragma unroll
  for (int i = 0; i < 12; ++i) { s1 += __expf(a[i] - m1); s2 += __expf(b[i] - m2); }
  #pragma unroll
  for (int d = 1; d < 64; d <<= 1) { s1 += __shfl_xor(s1, d); s2 += __shfl_xor(s2, d); }
  float c1 = g1 / s1, c2 = g2 / s2;
  float4* yo = (float4*)(y + (size_t)tok * D_OUT);
  #pragma unroll
  for (int i = 0; i < 3; ++i) {
    float4 o;
    float* op = (float*)&o;
    #pragma unroll
    for (int j = 0; j < 4; ++j) {
      float cmb = c1 * __expf(a[i * 4 + j] - m1) + c2 * __expf(b[i * 4 + j] - m2);
      op[j] = logf(cmb == 0.f ? 2.2204460492503131e-16f : cmb);
    }
    yo[l + i * 64] = o;
  }
}

// ---------------------------------------------------------------- launch
extern "C" void kernel_launch(void* const* d_in, const int* in_sizes, int n_in,
                              void* d_out, int out_size, void* d_ws, size_t ws_size,
                              hipStream_t stream) {
  const float* x  = (const float*)d_in[0];
  const float* wg = (const float*)d_in[1];
  const float* W1 = (const float*)d_in[2];
  const float* b1 = (const float*)d_in[3];
  const float* W2 = (const float*)d_in[4];
  const float* b2 = (const float*)d_in[5];
  float* out = (float*)d_out;

  char* ws = (char*)d_ws;
  int*   cnt_off = (int*)(ws + 0);                // [16]: counts then offsets
  float* gates   = (float*)(ws + 256);            // 4096*2 f32
  int*   tidx    = (int*)(ws + 256 + 32768);
  int*   pos     = (int*)(ws + 256 + 65536);
  int*   row_ids = (int*)(ws + 256 + 98304);
  int*   tmap    = (int*)(ws + 256 + 131072);     // [2*MAXT]
  const size_t base = 262144;
  bf16* x_bf = (bf16*)(ws + base);                        //  6,291,456 B
  bf16* W1t  = (bf16*)(ws + base + 6291456);              // 25,165,824 B
  bf16* W2t  = (bf16*)(ws + base + 31457280);             // 25,165,824 B
  bf16* h_bf = (bf16*)(ws + base + 56623104);             // 33,554,432 B
  bf16* z_bf = (bf16*)(ws + base);                        // aliases x_bf/W1t (dead by GEMM2)

  prep_kernel<<<dim3(4096), 256, 0, stream>>>(x, wg, W1, W1t, x_bf, gates, tidx);
  finalize_kernel<<<dim3(1), 256, 0, stream>>>(tidx, gates, cnt_off, row_ids, pos, tmap,
                                               out + (size_t)B_TOK * D_OUT);
  // GEMM1 (+ W2 transpose fused on tail grid rows: 48 x 16 = 768 blocks)
  gemm_bk32<D_IN, true, true, true><<<dim3(D_H / 128, MAXT + 48), 256, 0, stream>>>(
      x_bf, W1t, b1, h_bf, row_ids, cnt_off, tmap, D_H, W2, W2t);
  gemm_bk32<D_H, false, false, false><<<dim3(D_OUT / 128, MAXT), 256, 0, stream>>>(
      h_bf, W2t, b2, z_bf, row_ids, cnt_off, tmap, D_OUT, nullptr, nullptr);
  combine_kernel<<<dim3(1024), 256, 0, stream>>>(z_bf, gates, pos, out);
}